// Round 8
// baseline (551.991 us; speedup 1.0000x reference)
//
#include <hip/hip_runtime.h>
#include <hip/hip_bf16.h>
#include <hip/hip_fp16.h>

#define T_SEQ 4096
#define CDIM  768
#define BDIM  8
#define MROWS (BDIM * T_SEQ)   // 32768
#define NKVR  (3 * CDIM)       // 2304
#define CHL   32               // chunk length (half a raster row)
#define NCH   (T_SEQ / CHL)    // 128 chunks
#define BC    (BDIM * CDIM)    // 6144 independent recurrences
#define BC2   (BC / 2)         // 3072 channel-pairs
#define CD2   (CDIM / 2)       // 384
#define NKT32 (CDIM / 32)      // 24 K-tiles of 32

typedef __attribute__((ext_vector_type(8))) short   short8;
typedef __attribute__((ext_vector_type(4))) float   floatx4;
typedef unsigned short ushort_t;
typedef unsigned int   uint_t;

__device__ __forceinline__ ushort_t f2b(float f) {
    __hip_bfloat16 h = __float2bfloat16(f);
    return *(ushort_t*)&h;
}
__device__ __forceinline__ float b2f(ushort_t s) {
    __hip_bfloat16 h;
    *(ushort_t*)&h = s;
    return __bfloat162float(h);
}
__device__ __forceinline__ ushort_t f2h(float f) {
    __half h = __float2half(f);
    return *(ushort_t*)&h;
}
__device__ __forceinline__ float h2f(ushort_t s) {
    __half h;
    *(ushort_t*)&h = s;
    return __half2float(h);
}

__device__ __forceinline__ void gload_lds16(const void* g, void* l) {
    __builtin_amdgcn_global_load_lds(
        (const __attribute__((address_space(1))) void*)g,
        (__attribute__((address_space(3))) void*)l, 16, 0, 0);
}

// SHIFTS table: channel group i = c/32 gets shift (dy, dx); out[y][x] = in[y-dy][x-dx]
__constant__ int c_dy[24] = {0,0,1,-1,1,-1,1,-1,0,0,2,-2,2,-2,2,-2,2,1,2,1,-2,-1,-2,-1};
__constant__ int c_dx[24] = {1,-1,0,0,1,-1,-1,1,2,-2,0,0,2,-2,-2,2,1,2,-1,-2,1,2,-1,-2};

// ---------------------------------------------------------------- weights -> bf16
__global__ void cvt_weights(const float* __restrict__ kw, const float* __restrict__ vw,
                            const float* __restrict__ rw, const float* __restrict__ ow,
                            ushort_t* __restrict__ wkvr, ushort_t* __restrict__ wo) {
    int i = blockIdx.x * 256 + threadIdx.x;
    if (i < CDIM * CDIM) {
        wkvr[i]                   = f2b(kw[i]);
        wkvr[i + CDIM * CDIM]     = f2b(vw[i]);
        wkvr[i + 2 * CDIM * CDIM] = f2b(rw[i]);
        wo[i]                     = f2b(ow[i]);
    }
}

// ------------------------------------------------- shift + zigzag reorder + bf16
// 8 channels/thread (all in one shift group since 8 | 32): one bounds check,
// two float4 loads, one 16B store.
__global__ void shift_zigzag(const float* __restrict__ x, ushort_t* __restrict__ xs) {
    size_t i = (size_t)blockIdx.x * 256 + threadIdx.x;   // over MROWS*CDIM/8
    int c8 = (int)(i % (CDIM / 8)) * 8;
    size_t bt = i / (CDIM / 8);
    int tz = (int)(bt % T_SEQ);
    int b  = (int)(bt / T_SEQ);
    int r = tz >> 6, pos = tz & 63;
    int xcol = (r & 1) ? (63 - pos) : pos;
    int g = c8 >> 5;
    int ys = r - c_dy[g];
    int xsrc = xcol - c_dx[g];
    float4 v0 = {0.f, 0.f, 0.f, 0.f}, v1 = {0.f, 0.f, 0.f, 0.f};
    if ((unsigned)ys < 64u && (unsigned)xsrc < 64u) {
        const float* src = x + ((size_t)b * T_SEQ + (size_t)(ys * 64 + xsrc)) * CDIM + c8;
        v0 = *(const float4*)(src);
        v1 = *(const float4*)(src + 4);
    }
    short8 o;
    o[0] = (short)f2b(v0.x); o[1] = (short)f2b(v0.y);
    o[2] = (short)f2b(v0.z); o[3] = (short)f2b(v0.w);
    o[4] = (short)f2b(v1.x); o[5] = (short)f2b(v1.y);
    o[6] = (short)f2b(v1.z); o[7] = (short)f2b(v1.w);
    *(short8*)(xs + bt * CDIM + c8) = o;
}

// ---------------------------------------------------------------- bf16 MFMA GEMM
// r8: T3-minimum pipelined loop (catalog §5.5: proper-order 2-phase = 92% of
// 8-phase). 128x128 tile, BK=32, DOUBLE-buffered LDS (As/Bs[2][128*32] = 32KB
// -> keeps 3 blocks/CU), 256 thr. Per iteration: {STAGE(next buf);
// read frags(cur); 16 MFMA; sync} — ONE barrier/iter; the compiler's
// vmcnt(0)+lgkmcnt(0) drain before s_barrier is now covered by 8 ds_reads +
// 16 MFMAs instead of draining immediately after issue (the r3 2-barrier
// structure exposed full load latency every K-tile).
// Race audit: stage(kt+1) writes buf[(kt+1)&1], last read at kt-1 and ordered
// by barrier(kt-1) before the write-issue; drained by barrier(kt) before its
// first read at kt+1. Single barrier is sufficient.
// Swizzle for 64B rows: chunk c stored at slot c ^ ((row>>1)&3) (stage source
// pre-swizzled, LDS linear); reads un-swizzle -> exactly 2-way bank aliasing
// (free, m136). kb/vb/srb [t][c] planes (r6 T-major regressed: partial-line RMW).
// MODE 0 (NB=18): nb/6==0 -> k (fp16), ==1 -> v (fp16), ==2 -> sigmoid(r) bf16.
// MODE 1 (NB=6): fp32 out.
template <int MODE, int NB>
__device__ __forceinline__ void gemm_body(
    const ushort_t* __restrict__ A, const ushort_t* __restrict__ Bw,
    ushort_t* __restrict__ kbuf, ushort_t* __restrict__ vbuf,
    ushort_t* __restrict__ out_sr, float* __restrict__ out_f) {
    __shared__ ushort_t As[2][128 * 32];
    __shared__ ushort_t Bs[2][128 * 32];
    const int p    = blockIdx.x;
    const int xcd  = p & 7;
    const int s    = p >> 3;
    const int mb   = xcd + 8 * (s / NB);
    const int nb   = s % NB;
    const int m0   = mb * 128;
    const int n0   = nb * 128;
    const int t    = threadIdx.x;
    const int lane = t & 63;
    const int wv   = t >> 6;
    const int wm   = (wv & 1) * 64;
    const int wn   = (wv >> 1) * 64;
    const int l15  = lane & 15;
    const int l4   = lane >> 4;

    // staging geometry: 512 chunks of 16B per matrix per K-tile; 2 per thread
    const int ci0 = t;          // chunks t and t+256
    const int r0  = ci0 >> 2, s0 = ci0 & 3;
    const int ci1 = t + 256;
    const int r1  = ci1 >> 2, s1 = ci1 & 3;
    const int gc0 = s0 ^ ((r0 >> 1) & 3);
    const int gc1 = s1 ^ ((r1 >> 1) & 3);

    floatx4 acc[4][4];
#pragma unroll
    for (int i = 0; i < 4; i++)
#pragma unroll
        for (int j = 0; j < 4; j++) acc[i][j] = (floatx4){0.f, 0.f, 0.f, 0.f};

#define STAGE32(BUF, KK)                                                     \
    {                                                                        \
        gload_lds16(A  + (size_t)(m0 + r0) * CDIM + (KK) + gc0 * 8,          \
                    (void*)(&As[(BUF)][0] + ci0 * 8));                       \
        gload_lds16(A  + (size_t)(m0 + r1) * CDIM + (KK) + gc1 * 8,          \
                    (void*)(&As[(BUF)][0] + ci1 * 8));                       \
        gload_lds16(Bw + (size_t)(n0 + r0) * CDIM + (KK) + gc0 * 8,          \
                    (void*)(&Bs[(BUF)][0] + ci0 * 8));                       \
        gload_lds16(Bw + (size_t)(n0 + r1) * CDIM + (KK) + gc1 * 8,          \
                    (void*)(&Bs[(BUF)][0] + ci1 * 8));                       \
    }

    // prologue: stage K-tile 0 into buf 0; drain; barrier
    STAGE32(0, 0)
    __syncthreads();

    for (int kt = 0; kt < NKT32; kt++) {
        const int cur = kt & 1;
        if (kt + 1 < NKT32) STAGE32(cur ^ 1, (kt + 1) * 32)
        short8 af[4], bfv[4];
#pragma unroll
        for (int mi = 0; mi < 4; mi++) {
            int ra = wm + mi * 16 + l15;
            af[mi] = *(const short8*)(&As[cur][0] + ra * 32 +
                                      ((l4 ^ ((ra >> 1) & 3)) << 3));
        }
#pragma unroll
        for (int ni = 0; ni < 4; ni++) {
            int rb = wn + ni * 16 + l15;
            bfv[ni] = *(const short8*)(&Bs[cur][0] + rb * 32 +
                                       ((l4 ^ ((rb >> 1) & 3)) << 3));
        }
#pragma unroll
        for (int mi = 0; mi < 4; mi++)
#pragma unroll
            for (int ni = 0; ni < 4; ni++)
                acc[mi][ni] = __builtin_amdgcn_mfma_f32_16x16x32_bf16(
                    af[mi], bfv[ni], acc[mi][ni], 0, 0, 0);
        __syncthreads();   // compiler emits vmcnt(0)+lgkmcnt(0) drain here,
                           // covered by the 8 ds_reads + 16 MFMAs above
    }
#undef STAGE32

    const int region = (MODE == 0) ? (nb / 6) : 0;
    const int ncb = n0 - region * CDIM;
#pragma unroll
    for (int mi = 0; mi < 4; mi++) {
#pragma unroll
        for (int ni = 0; ni < 4; ni++) {
            int nc = ncb + wn + ni * 16 + l15;
#pragma unroll
            for (int r = 0; r < 4; r++) {
                int mg = m0 + wm + mi * 16 + l4 * 4 + r;
                float val = acc[mi][ni][r];
                if (MODE == 0) {
                    if (region == 0)
                        kbuf[(size_t)mg * CDIM + nc] = f2h(val);
                    else if (region == 1)
                        vbuf[(size_t)mg * CDIM + nc] = f2h(val);
                    else
                        out_sr[(size_t)mg * CDIM + nc] =
                            f2b(1.0f / (1.0f + __expf(-val)));
                } else {
                    out_f[(size_t)mg * CDIM + (n0 + wn + ni * 16 + l15)] = val;
                }
            }
        }
    }
}

__global__ __launch_bounds__(256, 3) void gemm_kvr(
    const ushort_t* __restrict__ A, const ushort_t* __restrict__ Bw,
    ushort_t* __restrict__ kbuf, ushort_t* __restrict__ vbuf,
    ushort_t* __restrict__ out_sr) {
    gemm_body<0, 18>(A, Bw, kbuf, vbuf, out_sr, nullptr);
}

__global__ __launch_bounds__(256, 3) void gemm_out(
    const ushort_t* __restrict__ A, const ushort_t* __restrict__ Bw,
    float* __restrict__ out_f) {
    gemm_body<1, 6>(A, Bw, nullptr, nullptr, nullptr, out_f);
}

// ------------------------------------------------------------- WKV chunked scan
// Recurrence: P' = e^w P + e^k v ; state max-normalized as (p,q,o).
// kb / vb: separate fp16 [t][c] planes. vb overwritten with y by pass-0 replay.
// PASS 0 sequence = zigzag row order (buffer row order).
// PASS 1 sequence = raster order; CHL=32 chunk remap (verified):
//   pass-1 chunk ch's rows form pass-2 chunk idx2 = (ch&2) ? ch^1 : ch,
//   traversed in reverse iff (ch>>1)&1.
// 2 adjacent channels/thread via packed-fp16 uint loads (G13). replay0_sum1
// register arrays PACKED as uint and pass-2 statically indexed via uniform-rev
// branch with two fully-unrolled loops (rule #20 fix, r7: -40us verified).
// ch = gid / BC2 is block-uniform (BC2 % 256 == 0) -> branch non-divergent.

// Phase A (pass 0): per-chunk local summary from empty state. 2 ch/thread.
__global__ __launch_bounds__(256) void wkv_chunk_sum0(
    const ushort_t* __restrict__ kb, const ushort_t* __restrict__ vb,
    const float* __restrict__ sd,
    float* __restrict__ sumP, float* __restrict__ sumQ, float* __restrict__ sumO) {
    int gid = blockIdx.x * 256 + threadIdx.x;   // over NCH*BC2
    int bc2 = gid % BC2;
    int ch  = gid / BC2;
    int b = bc2 / CD2, cp = (bc2 % CD2) * 2;
    const float w0 = sd[cp]     * (1.0f / (float)T_SEQ);
    const float w1 = sd[cp + 1] * (1.0f / (float)T_SEQ);
    const size_t base = ((size_t)b * T_SEQ + ch * CHL) * CDIM + cp;
    const uint_t* kp = (const uint_t*)(kb + base);
    const uint_t* vp = (const uint_t*)(vb + base);
    float p0 = 0.f, q0 = 0.f, o0 = -1e38f;
    float p1 = 0.f, q1 = 0.f, o1 = -1e38f;
#pragma unroll 8
    for (int i = 0; i < CHL; i++) {
        uint_t ku = kp[(size_t)i * CD2], vu = vp[(size_t)i * CD2];
        float k0 = h2f((ushort_t)(ku & 0xffff)), k1 = h2f((ushort_t)(ku >> 16));
        float v0 = h2f((ushort_t)(vu & 0xffff)), v1 = h2f((ushort_t)(vu >> 16));
        float wo0 = w0 + o0, wo1 = w1 + o1;
        float n0_ = fmaxf(wo0, k0), n1_ = fmaxf(wo1, k1);
        float A0 = __expf(wo0 - n0_), B0 = __expf(k0 - n0_);
        float A1 = __expf(wo1 - n1_), B1 = __expf(k1 - n1_);
        p0 = A0 * p0 + B0 * v0;  q0 = A0 * q0 + B0;  o0 = n0_;
        p1 = A1 * p1 + B1 * v1;  q1 = A1 * q1 + B1;  o1 = n1_;
    }
    size_t idx = (size_t)ch * BC + (size_t)b * CDIM + cp;   // even -> 8B aligned
    *(float2*)(sumP + idx) = make_float2(p0, p1);
    *(float2*)(sumQ + idx) = make_float2(q0, q1);
    *(float2*)(sumO + idx) = make_float2(o0, o1);
}

// Phase B: sequential combine of chunk summaries; writes incoming state per chunk.
__global__ __launch_bounds__(256) void wkv_chunk_scan(
    const float* __restrict__ sumP, const float* __restrict__ sumQ,
    const float* __restrict__ sumO,
    float* __restrict__ inP, float* __restrict__ inQ, float* __restrict__ inO,
    const float* __restrict__ sd, int pass) {
    int bc = blockIdx.x * 256 + threadIdx.x;
    if (bc >= BC) return;
    int c = bc % CDIM;
    const float w = sd[pass * CDIM + c] * (1.0f / (float)T_SEQ);
    const float Lw = w * (float)CHL;
    float p = 0.f, q = 0.f, o = -1e38f;
#pragma unroll 4
    for (int ch = 0; ch < NCH; ch++) {
        size_t idx = (size_t)ch * BC + bc;
        inP[idx] = p; inQ[idx] = q; inO[idx] = o;
        float Pc = sumP[idx], Qc = sumQ[idx], Oc = sumO[idx];
        float ow_ = o + Lw;
        float no = fmaxf(ow_, Oc);
        float e1 = __expf(ow_ - no), e2 = __expf(Oc - no);
        p = e1 * p + e2 * Pc;
        q = e1 * q + e2 * Qc;
        o = no;
    }
}

// Phase C fused: replay pass-0 chunk (y -> vb packed 4B stores, k/y kept in
// PACKED uint registers, FULLY unrolled), then pass-2 chunk summary over the
// same rows in raster traversal. 2 ch/thread. Pass-2 statically indexed.
__global__ __launch_bounds__(256) void wkv_replay0_sum1(
    const ushort_t* __restrict__ kb, ushort_t* __restrict__ vb,
    const float* __restrict__ sd, const float* __restrict__ sf,
    const float* __restrict__ inP, const float* __restrict__ inQ,
    const float* __restrict__ inO,
    float* __restrict__ sumP, float* __restrict__ sumQ, float* __restrict__ sumO) {
    int gid = blockIdx.x * 256 + threadIdx.x;   // over NCH*BC2
    int bc2 = gid % BC2;
    int ch  = gid / BC2;                         // block-uniform
    int b = bc2 / CD2, cp = (bc2 % CD2) * 2;
    const float w10 = sd[cp]     * (1.0f / (float)T_SEQ);
    const float w11 = sd[cp + 1] * (1.0f / (float)T_SEQ);
    const float u10 = sf[cp]     * (1.0f / (float)T_SEQ);
    const float u11 = sf[cp + 1] * (1.0f / (float)T_SEQ);
    const size_t base = ((size_t)b * T_SEQ + ch * CHL) * CDIM + cp;
    const uint_t* kp = (const uint_t*)(kb + base);
    uint_t* vp = (uint_t*)(vb + base);
    size_t idx = (size_t)ch * BC + (size_t)b * CDIM + cp;   // even
    float2 pin = *(const float2*)(inP + idx);
    float2 qin = *(const float2*)(inQ + idx);
    float2 oin = *(const float2*)(inO + idx);
    float p0 = pin.x, q0 = qin.x, o0 = oin.x;
    float p1 = pin.y, q1 = qin.y, o1 = oin.y;
    uint_t ku_[CHL];   // packed k (fp16 x2)
    uint_t yu_[CHL];   // packed y (fp16 x2)
#pragma unroll
    for (int i = 0; i < CHL; i++) {
        uint_t ku = kp[(size_t)i * CD2];
        uint_t vu = vp[(size_t)i * CD2];
        ku_[i] = ku;
        float k0 = h2f((ushort_t)(ku & 0xffff)), k1 = h2f((ushort_t)(ku >> 16));
        float v0 = h2f((ushort_t)(vu & 0xffff)), v1 = h2f((ushort_t)(vu >> 16));
        // channel 0
        float uk0 = u10 + k0;
        float no0 = fmaxf(o0, uk0);
        float Ae0 = __expf(o0 - no0), Be0 = __expf(uk0 - no0);
        float y0 = (Ae0 * p0 + Be0 * v0) / (Ae0 * q0 + Be0);
        float wo0 = w10 + o0;
        float nn0 = fmaxf(wo0, k0);
        float A20 = __expf(wo0 - nn0), B20 = __expf(k0 - nn0);
        p0 = A20 * p0 + B20 * v0;  q0 = A20 * q0 + B20;  o0 = nn0;
        // channel 1
        float uk1 = u11 + k1;
        float no1 = fmaxf(o1, uk1);
        float Ae1 = __expf(o1 - no1), Be1 = __expf(uk1 - no1);
        float y1 = (Ae1 * p1 + Be1 * v1) / (Ae1 * q1 + Be1);
        float wo1 = w11 + o1;
        float nn1 = fmaxf(wo1, k1);
        float A21 = __expf(wo1 - nn1), B21 = __expf(k1 - nn1);
        p1 = A21 * p1 + B21 * v1;  q1 = A21 * q1 + B21;  o1 = nn1;
        uint_t yu = (uint_t)f2h(y0) | ((uint_t)f2h(y1) << 16);
        yu_[i] = yu;
        vp[(size_t)i * CD2] = yu;   // overwrite v with y (4B store)
    }
    // pass-2 summary over same rows; raster traversal; uses fp16-rounded y
    // (== what replay1 reads back from vb). STATIC indexing via uniform branch.
    const float w20 = sd[CDIM + cp]     * (1.0f / (float)T_SEQ);
    const float w21 = sd[CDIM + cp + 1] * (1.0f / (float)T_SEQ);
    float p20 = 0.f, q20 = 0.f, o20 = -1e38f;
    float p21 = 0.f, q21 = 0.f, o21 = -1e38f;
#define P2STEP(I)                                                              \
    {                                                                          \
        uint_t ku = ku_[(I)], yu = yu_[(I)];                                   \
        float k0 = h2f((ushort_t)(ku & 0xffff)), k1 = h2f((ushort_t)(ku >> 16)); \
        float y0 = h2f((ushort_t)(yu & 0xffff)), y1 = h2f((ushort_t)(yu >> 16)); \
        float wo0 = w20 + o20, wo1 = w21 + o21;                                \
        float nn0 = fmaxf(wo0, k0), nn1 = fmaxf(wo1, k1);                      \
        float A20 = __expf(wo0 - nn0), B20 = __expf(k0 - nn0);                 \
        float A21 = __expf(wo1 - nn1), B21 = __expf(k1 - nn1);                 \
        p20 = A20 * p20 + B20 * y0;  q20 = A20 * q20 + B20;  o20 = nn0;        \
        p21 = A21 * p21 + B21 * y1;  q21 = A21 * q21 + B21;  o21 = nn1;        \
    }
    if (((ch >> 1) & 1) == 0) {
#pragma unroll
        for (int j = 0; j < CHL; j++) P2STEP(j)
    } else {
#pragma unroll
        for (int j = 0; j < CHL; j++) P2STEP(CHL - 1 - j)
    }
#undef P2STEP
    size_t idx2 = (size_t)((ch & 2) ? (ch ^ 1) : ch) * BC + (size_t)b * CDIM + cp;
    *(float2*)(sumP + idx2) = make_float2(p20, p21);
    *(float2*)(sumQ + idx2) = make_float2(q20, q21);
    *(float2*)(sumO + idx2) = make_float2(o20, o21);
}

// Phase C (pass 1): replay raster-order chunk ch, emit a2 = bf16(y * sr).
// 2 ch/thread packed loads/stores.
__global__ __launch_bounds__(256) void wkv_replay1(
    const ushort_t* __restrict__ kb, const ushort_t* __restrict__ vb,
    const ushort_t* __restrict__ srb, ushort_t* __restrict__ a2,
    const float* __restrict__ sd, const float* __restrict__ sf,
    const float* __restrict__ inP, const float* __restrict__ inQ,
    const float* __restrict__ inO) {
    int gid = blockIdx.x * 256 + threadIdx.x;   // over NCH*BC2
    int bc2 = gid % BC2;
    int ch  = gid / BC2;
    int b = bc2 / CD2, cp = (bc2 % CD2) * 2;
    const float w0 = sd[CDIM + cp]     * (1.0f / (float)T_SEQ);
    const float w1 = sd[CDIM + cp + 1] * (1.0f / (float)T_SEQ);
    const float u0 = sf[CDIM + cp]     * (1.0f / (float)T_SEQ);
    const float u1 = sf[CDIM + cp + 1] * (1.0f / (float)T_SEQ);
    size_t base = (size_t)b * T_SEQ * CDIM + cp;
    size_t idx = (size_t)ch * BC + (size_t)b * CDIM + cp;   // even
    float2 pin = *(const float2*)(inP + idx);
    float2 qin = *(const float2*)(inQ + idx);
    float2 oin = *(const float2*)(inO + idx);
    float p0 = pin.x, q0 = qin.x, o0 = oin.x;
    float p1 = pin.y, q1 = qin.y, o1 = oin.y;
    const int r = ch >> 1;
    const int pos0 = (ch & 1) * CHL;
#pragma unroll 8
    for (int i = 0; i < CHL; i++) {
        int pos = pos0 + i;
        int col = (r & 1) ? (63 - pos) : pos;
        size_t off = base + (size_t)(r * 64 + col) * CDIM;
        uint_t ku = *(const uint_t*)(kb + off);
        uint_t vu = *(const uint_t*)(vb + off);
        uint_t su = *(const uint_t*)(srb + off);
        float k0 = h2f((ushort_t)(ku & 0xffff)), k1 = h2f((ushort_t)(ku >> 16));
        float v0 = h2f((ushort_t)(vu & 0xffff)), v1 = h2f((ushort_t)(vu >> 16));
        // channel 0
        float uk0 = u0 + k0;
        float no0 = fmaxf(o0, uk0);
        float Ae0 = __expf(o0 - no0), Be0 = __expf(uk0 - no0);
        float y0 = (Ae0 * p0 + Be0 * v0) / (Ae0 * q0 + Be0);
        float wo0 = w0 + o0;
        float nn0 = fmaxf(wo0, k0);
        float A20 = __expf(wo0 - nn0), B20 = __expf(k0 - nn0);
        p0 = A20 * p0 + B20 * v0;  q0 = A20 * q0 + B20;  o0 = nn0;
        // channel 1
        float uk1 = u1 + k1;
        float no1 = fmaxf(o1, uk1);
        float Ae1 = __expf(o1 - no1), Be1 = __expf(uk1 - no1);
        float y1 = (Ae1 * p1 + Be1 * v1) / (Ae1 * q1 + Be1);
        float wo1 = w1 + o1;
        float nn1 = fmaxf(wo1, k1);
        float A21 = __expf(wo1 - nn1), B21 = __expf(k1 - nn1);
        p1 = A21 * p1 + B21 * v1;  q1 = A21 * q1 + B21;  o1 = nn1;
        uint_t out = (uint_t)f2b(y0 * b2f((ushort_t)(su & 0xffff))) |
                     ((uint_t)f2b(y1 * b2f((ushort_t)(su >> 16))) << 16);
        *(uint_t*)(a2 + off) = out;
    }
}

// ----------------------------------------------------------------------- launch
extern "C" void kernel_launch(void* const* d_in, const int* in_sizes, int n_in,
                              void* d_out, int out_size, void* d_ws, size_t ws_size,
                              hipStream_t stream) {
    (void)in_sizes; (void)n_in; (void)out_size; (void)ws_size;
    const float* x  = (const float*)d_in[0];
    const float* kw = (const float*)d_in[1];
    const float* vw = (const float*)d_in[2];
    const float* rw = (const float*)d_in[3];
    const float* ow = (const float*)d_in[4];
    const float* sd = (const float*)d_in[5];
    const float* sf = (const float*)d_in[6];
    float* out = (float*)d_out;

    char* ws = (char*)d_ws;
    size_t off = 0;
    auto alloc = [&](size_t bytes) -> void* {
        void* p = ws + off;
        off += (bytes + 255) & ~(size_t)255;
        return p;
    };
    ushort_t* xs   = (ushort_t*)alloc((size_t)MROWS * CDIM * 2);  // reused as a2
    ushort_t* kb   = (ushort_t*)alloc((size_t)MROWS * CDIM * 2);  // k fp16
    ushort_t* vb   = (ushort_t*)alloc((size_t)MROWS * CDIM * 2);  // v / y fp16
    ushort_t* srb  = (ushort_t*)alloc((size_t)MROWS * CDIM * 2);  // bf16
    ushort_t* wkvr = (ushort_t*)alloc((size_t)NKVR * CDIM * 2);
    ushort_t* wo   = (ushort_t*)alloc((size_t)CDIM * CDIM * 2);
    float*    sumP = (float*)   alloc((size_t)NCH * BC * 4);
    float*    sumQ = (float*)   alloc((size_t)NCH * BC * 4);
    float*    sumO = (float*)   alloc((size_t)NCH * BC * 4);
    float*    inP  = (float*)   alloc((size_t)NCH * BC * 4);
    float*    inQ  = (float*)   alloc((size_t)NCH * BC * 4);
    float*    inO  = (float*)   alloc((size_t)NCH * BC * 4);

    cvt_weights<<<(CDIM * CDIM + 255) / 256, 256, 0, stream>>>(kw, vw, rw, ow, wkvr, wo);
    shift_zigzag<<<(int)((size_t)MROWS * (CDIM / 8) / 256), 256, 0, stream>>>(x, xs);
    gemm_kvr<<<(MROWS / 128) * (NKVR / 128), 256, 0, stream>>>(
        xs, wkvr, kb, vb, srb);

    const int nwkv2 = NCH * BC2;  // 393216 threads (2-ch kernels)
    wkv_chunk_sum0<<<nwkv2 / 256, 256, 0, stream>>>(kb, vb, sd, sumP, sumQ, sumO);
    wkv_chunk_scan<<<(BC + 255) / 256, 256, 0, stream>>>(sumP, sumQ, sumO,
                                                         inP, inQ, inO, sd, 0);
    wkv_replay0_sum1<<<nwkv2 / 256, 256, 0, stream>>>(kb, vb, sd, sf,
                                                      inP, inQ, inO, sumP, sumQ, sumO);
    wkv_chunk_scan<<<(BC + 255) / 256, 256, 0, stream>>>(sumP, sumQ, sumO,
                                                         inP, inQ, inO, sd, 1);
    wkv_replay1<<<nwkv2 / 256, 256, 0, stream>>>(kb, vb, srb, xs,
                                                 sd, sf, inP, inQ, inO);

    gemm_out<<<(MROWS / 128) * (CDIM / 128), 256, 0, stream>>>(xs, wo, out);
}